// Round 4
// baseline (1041.737 us; speedup 1.0000x reference)
//
#include <hip/hip_runtime.h>
#include <hip/hip_bf16.h>
#include <stdint.h>

// TemporalAttention for MI355X (gfx950). B=16, N=256, T=128, H=128.
// R4: two barrier-free kernels (K1 proj, K2 attn), wave-private LDS only,
//     Q/K/V^T handed off via workspace (406MB); poly-erf GELU (no libcall).
//     Falls back to R3 fused kernel if ws_size too small.

typedef __bf16 bf16;
typedef __bf16 bf16x4 __attribute__((ext_vector_type(4)));
typedef __bf16 bf16x8 __attribute__((ext_vector_type(8)));
typedef float  f32x4  __attribute__((ext_vector_type(4)));

#define MFMA16(a, b, c) __builtin_amdgcn_mfma_f32_16x16x32_bf16((a), (b), (c), 0, 0, 0)

__device__ __forceinline__ int allBytesNonzero(unsigned v) {
    return ((v - 0x01010101u) & ~v & 0x80808080u) == 0u;
}

__device__ __forceinline__ bf16x8 cvt8(const float* p) {
    float4 f0 = *reinterpret_cast<const float4*>(p);
    float4 f1 = *reinterpret_cast<const float4*>(p + 4);
    bf16x8 r;
    r[0] = (bf16)f0.x; r[1] = (bf16)f0.y; r[2] = (bf16)f0.z; r[3] = (bf16)f0.w;
    r[4] = (bf16)f1.x; r[5] = (bf16)f1.y; r[6] = (bf16)f1.z; r[7] = (bf16)f1.w;
    return r;
}

// branchless erf-GELU, A&S 7.1.26 (|err| < 1.5e-7)
__device__ __forceinline__ float gelu_erf(float v) {
    float x  = v * 0.70710678118654752f;
    float ax = fabsf(x);
    float t  = __builtin_amdgcn_rcpf(1.0f + 0.3275911f * ax);
    float p  = ((((1.061405429f * t - 1.453152027f) * t + 1.421413741f) * t
                 - 0.284496736f) * t + 0.254829592f) * t;
    float er = 1.0f - p * __expf(-ax * ax);
    er = copysignf(er, x);
    return 0.5f * v * (1.0f + er);
}

// ---- pre-kernel 1: transpose W1(=W_in[0:128]), Wq, Wk, Wv, Wo to bf16 [h][k] ----
__global__ void prep_weights(const float* __restrict__ W_in,
                             const float* __restrict__ Wq, const float* __restrict__ Wk,
                             const float* __restrict__ Wv, const float* __restrict__ Wo,
                             bf16* __restrict__ dst)
{
    int idx = blockIdx.x * 256 + threadIdx.x;
    if (idx >= 5 * 16384) return;
    int m = idx >> 14, r = idx & 16383;
    int h = r >> 7, k = r & 127;
    const float* src = (m == 0) ? W_in : (m == 1) ? Wq : (m == 2) ? Wk : (m == 3) ? Wv : Wo;
    dst[(m << 14) + h * 128 + k] = (bf16)src[k * 128 + h];  // dst[m][h][k] = W[k][h]
}

// ---- pre-kernel 2: npart[n][h] = E_node[nf[n]] @ W_in[256:384] (f32) ----
__global__ void prep_npart(const int* __restrict__ nf, const float* __restrict__ E_node,
                           const float* __restrict__ W_in, float* __restrict__ npart)
{
    int n = blockIdx.x, h = threadIdx.x;
    int node = nf[n];
    const float* e = E_node + node * 128;
    float acc = 0.f;
    for (int k = 0; k < 128; ++k) acc += e[k] * W_in[(256 + k) * 128 + h];
    npart[n * 128 + h] = acc;
}

// ---- pre-kernel 3: biasT[b][h][t] (t fastest for float4 epilogue loads) ----
__global__ void prep_bias(const float* __restrict__ ex, const float* __restrict__ W_t,
                          const float* __restrict__ b_t, const float* __restrict__ W_in,
                          const float* __restrict__ b_in, float* __restrict__ biasT)
{
    const int bt = blockIdx.x;          // b*128 + t
    const int b = bt >> 7;
    const int t = bt & 127;
    const int h = threadIdx.x;
    __shared__ float te[128];
    float v = b_t[h];
    const float* exr = ex + (size_t)bt * 32;
    for (int d = 0; d < 32; ++d) v += exr[d] * W_t[d * 128 + h];
    te[h] = v;
    __syncthreads();
    float acc = b_in[h];
    const float ninv = -9.210340371976184f / 128.0f;   // -ln(10000)/H
    for (int j = 0; j < 64; ++j) {
        float div = expf((float)(2 * j) * ninv);
        float ang = (float)t * div;
        acc += sinf(ang) * W_in[(2 * j) * 128 + h] + cosf(ang) * W_in[(2 * j + 1) * 128 + h];
    }
    for (int k = 0; k < 128; ++k) acc += te[k] * W_in[(128 + k) * 128 + h];
    biasT[(size_t)b * 16384 + h * 128 + t] = acc;
}

// =====================================================================
// K1: projection. grid 8192 x 256thr; block = (bn, half); wave owns 16 rows.
// Zero barriers: all LDS is wave-private patches.
// MFMA 16x16x32: A row=lane&15,k=(lane>>4)*8+j; B col=lane&15; C/D col=lane&15,row=(lane>>4)*4+r.
// =====================================================================
__global__ __launch_bounds__(256, 4) void k1_proj(
    const float* __restrict__ xf, const unsigned char* __restrict__ mask,
    const bf16* __restrict__ wsW, const float* __restrict__ biasT,
    const float* __restrict__ npart,
    const float* __restrict__ bq, const float* __restrict__ bk,
    const float* __restrict__ bv,
    bf16* __restrict__ gQ, bf16* __restrict__ gK, bf16* __restrict__ gVT,
    float* __restrict__ gTm)
{
    const bf16* W1T = wsW;
    const bf16* WqT = wsW + 16384;
    const bf16* WkT = wsW + 32768;
    const bf16* WvT = wsW + 49152;

    __shared__ bf16 pX[4][16][136];   // wave-private X rows
    __shared__ bf16 pS[4][16][136];   // wave-private staging (Q then K)

    const int bid  = blockIdx.x;
    const int bn   = bid >> 1;
    const int half = bid & 1;
    const int b    = bn >> 8;
    const int n    = bn & 255;
    const int tid  = (int)threadIdx.x;
    const int w    = tid >> 6;
    const int lane = tid & 63;
    const int c    = lane & 15;
    const int g    = lane >> 4;
    const int s0   = half * 64 + w * 16;

    const f32x4 FZ = {0.f, 0.f, 0.f, 0.f};

    // ---- t_mask for this half's 64 t-rows ----
    if (tid < 64) {
        const int trow = half * 64 + tid;
        const uint4* mp = reinterpret_cast<const uint4*>(mask + ((size_t)bn * 128 + trow) * 128);
        int ok = 1;
        #pragma unroll
        for (int i = 0; i < 8; ++i) {
            uint4 u = mp[i];
            ok &= allBytesNonzero(u.x) & allBytesNonzero(u.y)
                & allBytesNonzero(u.z) & allBytesNonzero(u.w);
        }
        gTm[(size_t)bn * 128 + trow] = ok ? 1.0f : 0.0f;
    }

    // ---- GEMM1: X = gelu(xf@W1 + biasT + npart) -> pX[w] ----
    {
        f32x4 acc[8];
        #pragma unroll
        for (int ct = 0; ct < 8; ++ct) acc[ct] = FZ;
        const float* xfb = xf + (size_t)bn * 16384;
        #pragma unroll
        for (int kk = 0; kk < 4; ++kk) {
            const int k0 = kk * 32 + g * 8;
            bf16x8 a0 = cvt8(xfb + (s0 + c) * 128 + k0);
            #pragma unroll
            for (int ct = 0; ct < 8; ++ct) {
                bf16x8 bw = *reinterpret_cast<const bf16x8*>(W1T + (ct * 16 + c) * 128 + k0);
                acc[ct] = MFMA16(a0, bw, acc[ct]);
            }
        }
        const float* biasB = biasT + (size_t)b * 16384;
        const float* npRow = npart + n * 128;
        #pragma unroll
        for (int ct = 0; ct < 8; ++ct) {
            const int h = ct * 16 + c;
            const float npv = npRow[h];
            const float4 bb = *reinterpret_cast<const float4*>(biasB + h * 128 + s0 + g * 4);
            const float bbr[4] = {bb.x, bb.y, bb.z, bb.w};
            #pragma unroll
            for (int r = 0; r < 4; ++r)
                pX[w][g * 4 + r][h] = (bf16)gelu_erf(acc[ct][r] + bbr[r] + npv);
        }
    }

    // ---- Q = X@Wq + bq -> pS -> coalesced store gQ ----
    {
        f32x4 acc[8];
        #pragma unroll
        for (int ct = 0; ct < 8; ++ct) acc[ct] = FZ;
        #pragma unroll
        for (int kk = 0; kk < 4; ++kk) {
            const int k0 = kk * 32 + g * 8;
            bf16x8 a0 = *reinterpret_cast<const bf16x8*>(&pX[w][c][k0]);
            #pragma unroll
            for (int ct = 0; ct < 8; ++ct) {
                bf16x8 bw = *reinterpret_cast<const bf16x8*>(WqT + (ct * 16 + c) * 128 + k0);
                acc[ct] = MFMA16(a0, bw, acc[ct]);
            }
        }
        #pragma unroll
        for (int ct = 0; ct < 8; ++ct) {
            const int h = ct * 16 + c;
            const float bqv = bq[h];
            #pragma unroll
            for (int r = 0; r < 4; ++r)
                pS[w][g * 4 + r][h] = (bf16)(acc[ct][r] + bqv);
        }
        bf16* dst = gQ + (size_t)bn * 16384;
        #pragma unroll
        for (int i = 0; i < 4; ++i) {
            bf16x8 v8 = *reinterpret_cast<const bf16x8*>(&pS[w][i * 4 + g][c * 8]);
            *reinterpret_cast<bf16x8*>(dst + (s0 + i * 4 + g) * 128 + c * 8) = v8;
        }
    }

    // ---- K = X@Wk + bk -> pS -> coalesced store gK ----
    {
        f32x4 acc[8];
        #pragma unroll
        for (int ct = 0; ct < 8; ++ct) acc[ct] = FZ;
        #pragma unroll
        for (int kk = 0; kk < 4; ++kk) {
            const int k0 = kk * 32 + g * 8;
            bf16x8 a0 = *reinterpret_cast<const bf16x8*>(&pX[w][c][k0]);
            #pragma unroll
            for (int ct = 0; ct < 8; ++ct) {
                bf16x8 bw = *reinterpret_cast<const bf16x8*>(WkT + (ct * 16 + c) * 128 + k0);
                acc[ct] = MFMA16(a0, bw, acc[ct]);
            }
        }
        #pragma unroll
        for (int ct = 0; ct < 8; ++ct) {
            const int h = ct * 16 + c;
            const float bkv = bk[h];
            #pragma unroll
            for (int r = 0; r < 4; ++r)
                pS[w][g * 4 + r][h] = (bf16)(acc[ct][r] + bkv);
        }
        bf16* dst = gK + (size_t)bn * 16384;
        #pragma unroll
        for (int i = 0; i < 4; ++i) {
            bf16x8 v8 = *reinterpret_cast<const bf16x8*>(&pS[w][i * 4 + g][c * 8]);
            *reinterpret_cast<bf16x8*>(dst + (s0 + i * 4 + g) * 128 + c * 8) = v8;
        }
    }

    // ---- V = X@Wv + bv -> V^T[h][t] via 8B scattered stores (L2 merges) ----
    {
        f32x4 acc[8];
        #pragma unroll
        for (int ct = 0; ct < 8; ++ct) acc[ct] = FZ;
        #pragma unroll
        for (int kk = 0; kk < 4; ++kk) {
            const int k0 = kk * 32 + g * 8;
            bf16x8 a0 = *reinterpret_cast<const bf16x8*>(&pX[w][c][k0]);
            #pragma unroll
            for (int ct = 0; ct < 8; ++ct) {
                bf16x8 bw = *reinterpret_cast<const bf16x8*>(WvT + (ct * 16 + c) * 128 + k0);
                acc[ct] = MFMA16(a0, bw, acc[ct]);
            }
        }
        bf16* dst = gVT + (size_t)bn * 16384;
        #pragma unroll
        for (int ct = 0; ct < 8; ++ct) {
            const float bvv = bv[ct * 16 + c];
            bf16x4 pk;
            #pragma unroll
            for (int r = 0; r < 4; ++r) pk[r] = (bf16)(acc[ct][r] + bvv);
            *reinterpret_cast<bf16x4*>(dst + (ct * 16 + c) * 128 + s0 + g * 4) = pk;
        }
    }
}

// =====================================================================
// K2: attention + out-proj. grid 8192 x 256thr; zero barriers; LDS = P patch.
// =====================================================================
__global__ __launch_bounds__(256, 4) void k2_attn(
    const bf16* __restrict__ gQ, const bf16* __restrict__ gK,
    const bf16* __restrict__ gVT, const float* __restrict__ gTm,
    const bf16* __restrict__ wsW, const float* __restrict__ bo,
    float* __restrict__ out)
{
    const bf16* WoT = wsW + 65536;
    __shared__ bf16 pP[4][16][136];   // wave-private: P then rec

    const int bid  = blockIdx.x;
    const int bn   = bid >> 1;
    const int half = bid & 1;
    const int tid  = (int)threadIdx.x;
    const int w    = tid >> 6;
    const int lane = tid & 63;
    const int c    = lane & 15;
    const int g    = lane >> 4;
    const int s0   = half * 64 + w * 16;

    const f32x4 FZ = {0.f, 0.f, 0.f, 0.f};
    const float rs = 0.08838834764831845f;  // 1/sqrt(128)

    const bf16* Qb  = gQ  + (size_t)bn * 16384;
    const bf16* Kb  = gK  + (size_t)bn * 16384;
    const bf16* VTb = gVT + (size_t)bn * 16384;
    const float* tm = gTm + (size_t)bn * 128;

    float l0 = 1.f;

    // ---- scores^T[t][s] = K·Q^T ; softmax over t ; P -> pP[w] rows=c(s), cols=t ----
    {
        f32x4 sc[8];
        #pragma unroll
        for (int rt = 0; rt < 8; ++rt) sc[rt] = FZ;
        #pragma unroll
        for (int kk = 0; kk < 4; ++kk) {
            const int k0 = kk * 32 + g * 8;
            bf16x8 q0 = *reinterpret_cast<const bf16x8*>(Qb + (s0 + c) * 128 + k0);
            #pragma unroll
            for (int rt = 0; rt < 8; ++rt) {
                bf16x8 akf = *reinterpret_cast<const bf16x8*>(Kb + (rt * 16 + c) * 128 + k0);
                sc[rt] = MFMA16(akf, q0, sc[rt]);
            }
        }
        float m = -3.0e38f;
        #pragma unroll
        for (int rt = 0; rt < 8; ++rt)
            #pragma unroll
            for (int r = 0; r < 4; ++r) m = fmaxf(m, sc[rt][r]);
        m = fmaxf(m, __shfl_xor(m, 16));
        m = fmaxf(m, __shfl_xor(m, 32));
        float ls = 0.f, wsum = 0.f;
        #pragma unroll
        for (int rt = 0; rt < 8; ++rt) {
            const float4 tm4 = *reinterpret_cast<const float4*>(tm + rt * 16 + g * 4);
            const float tmr[4] = {tm4.x, tm4.y, tm4.z, tm4.w};
            #pragma unroll
            for (int r = 0; r < 4; ++r) {
                float p = __expf((sc[rt][r] - m) * rs);
                sc[rt][r] = p;
                ls += p;
                wsum += p * tmr[r];
            }
        }
        ls   += __shfl_xor(ls, 16);   ls   += __shfl_xor(ls, 32);
        wsum += __shfl_xor(wsum, 16); wsum += __shfl_xor(wsum, 32);
        l0 = ls;
        if (g == 0)
            out[(size_t)67108864 + (size_t)bn * 128 + s0 + c] = 1.0f - wsum / ls;
        #pragma unroll
        for (int rt = 0; rt < 8; ++rt) {
            bf16x4 pk;
            #pragma unroll
            for (int r = 0; r < 4; ++r) pk[r] = (bf16)sc[rt][r];
            *reinterpret_cast<bf16x4*>(&pP[w][c][rt * 16 + g * 4]) = pk;
        }
    }

    // ---- rec^T[h][s] = V^T·P ; normalize ; rec -> pP[w] rows=c(s), cols=h ----
    {
        f32x4 rc[8];
        #pragma unroll
        for (int rt = 0; rt < 8; ++rt) rc[rt] = FZ;
        #pragma unroll
        for (int kk = 0; kk < 4; ++kk) {
            const int k0 = kk * 32 + g * 8;
            bf16x8 p0 = *reinterpret_cast<const bf16x8*>(&pP[w][c][k0]);
            #pragma unroll
            for (int rt = 0; rt < 8; ++rt) {
                bf16x8 avf = *reinterpret_cast<const bf16x8*>(VTb + (rt * 16 + c) * 128 + k0);
                rc[rt] = MFMA16(avf, p0, rc[rt]);
            }
        }
        const float inv0 = __builtin_amdgcn_rcpf(l0);
        #pragma unroll
        for (int rt = 0; rt < 8; ++rt) {
            bf16x4 pk0;
            #pragma unroll
            for (int r = 0; r < 4; ++r) pk0[r] = (bf16)(rc[rt][r] * inv0);
            *reinterpret_cast<bf16x4*>(&pP[w][c][rt * 16 + g * 4]) = pk0;
        }
    }

    // ---- out^T[ho][s] = Wo^T·rec^T + bo ; store f32 ----
    {
        f32x4 oc[8];
        #pragma unroll
        for (int rt = 0; rt < 8; ++rt) oc[rt] = FZ;
        #pragma unroll
        for (int kk = 0; kk < 4; ++kk) {
            const int k0 = kk * 32 + g * 8;
            bf16x8 r0 = *reinterpret_cast<const bf16x8*>(&pP[w][c][k0]);
            #pragma unroll
            for (int rt = 0; rt < 8; ++rt) {
                bf16x8 aw = *reinterpret_cast<const bf16x8*>(WoT + (rt * 16 + c) * 128 + k0);
                oc[rt] = MFMA16(aw, r0, oc[rt]);
            }
        }
        float* outb = out + (size_t)bn * 16384;
        const int s = s0 + c;
        #pragma unroll
        for (int rt = 0; rt < 8; ++rt) {
            const int ho0 = rt * 16 + g * 4;
            const float4 bo4 = *reinterpret_cast<const float4*>(bo + ho0);
            float4 v;
            v.x = oc[rt][0] + bo4.x;
            v.y = oc[rt][1] + bo4.y;
            v.z = oc[rt][2] + bo4.z;
            v.w = oc[rt][3] + bo4.w;
            *reinterpret_cast<float4*>(outb + s * 128 + ho0) = v;
        }
    }
}

// =====================================================================
// Fallback: R3 fused kernel (used only when ws_size is too small for split).
// =====================================================================
__global__ __launch_bounds__(512, 4) void fused_r3(
    const float* __restrict__ xf, const unsigned char* __restrict__ mask,
    const bf16* __restrict__ wsW, const float* __restrict__ biasT,
    const float* __restrict__ npart,
    const float* __restrict__ bq, const float* __restrict__ bk,
    const float* __restrict__ bv, const float* __restrict__ bo,
    float* __restrict__ out)
{
    const bf16* W1T = wsW;
    const bf16* WqT = wsW + 16384;
    const bf16* WkT = wsW + 32768;
    const bf16* WvT = wsW + 49152;
    const bf16* WoT = wsW + 65536;

    __shared__ bf16 sX[128][136];
    __shared__ bf16 sKV[128][136];
    __shared__ float sTm[128];

    const int bn = blockIdx.x;
    const int b  = bn >> 8;
    const int n  = bn & 255;
    const int tid  = (int)threadIdx.x;
    const int w    = tid >> 6;
    const int lane = tid & 63;
    const int c = lane & 15;
    const int g = lane >> 4;
    const int s0 = w << 4;

    const f32x4 FZ = {0.f, 0.f, 0.f, 0.f};

    if (tid < 128) {
        const uint4* mp = reinterpret_cast<const uint4*>(mask + ((size_t)bn * 128 + tid) * 128);
        int ok = 1;
        #pragma unroll
        for (int i = 0; i < 8; ++i) {
            uint4 u = mp[i];
            ok &= allBytesNonzero(u.x) & allBytesNonzero(u.y)
                & allBytesNonzero(u.z) & allBytesNonzero(u.w);
        }
        sTm[tid] = ok ? 1.0f : 0.0f;
    }

    {
        f32x4 acc[8];
        #pragma unroll
        for (int ct = 0; ct < 8; ++ct) acc[ct] = FZ;
        const float* xfb = xf + (size_t)bn * 16384;
        #pragma unroll
        for (int kk = 0; kk < 4; ++kk) {
            const int k0 = kk * 32 + g * 8;
            bf16x8 a0 = cvt8(xfb + (s0 + c) * 128 + k0);
            #pragma unroll
            for (int ct = 0; ct < 8; ++ct) {
                bf16x8 bw = *reinterpret_cast<const bf16x8*>(W1T + (ct * 16 + c) * 128 + k0);
                acc[ct] = MFMA16(a0, bw, acc[ct]);
            }
        }
        const float* biasB = biasT + (size_t)b * 16384;
        const float* npRow = npart + n * 128;
        #pragma unroll
        for (int ct = 0; ct < 8; ++ct) {
            const int h = ct * 16 + c;
            const float npv = npRow[h];
            const float4 bb = *reinterpret_cast<const float4*>(biasB + h * 128 + s0 + g * 4);
            const float bbr[4] = {bb.x, bb.y, bb.z, bb.w};
            #pragma unroll
            for (int r = 0; r < 4; ++r)
                sX[s0 + g * 4 + r][h] = (bf16)gelu_erf(acc[ct][r] + bbr[r] + npv);
        }
    }

    f32x4 aq[8];
    bf16x4 vpk[8];
    {
        #pragma unroll
        for (int ct = 0; ct < 8; ++ct) aq[ct] = FZ;
        #pragma unroll
        for (int kk = 0; kk < 4; ++kk) {
            const int k0 = kk * 32 + g * 8;
            bf16x8 a0 = *reinterpret_cast<const bf16x8*>(&sX[s0 + c][k0]);
            #pragma unroll
            for (int ct = 0; ct < 8; ++ct) {
                bf16x8 bw = *reinterpret_cast<const bf16x8*>(WqT + (ct * 16 + c) * 128 + k0);
                aq[ct] = MFMA16(a0, bw, aq[ct]);
            }
        }
    }
    {
        f32x4 ak[8];
        #pragma unroll
        for (int ct = 0; ct < 8; ++ct) ak[ct] = FZ;
        #pragma unroll
        for (int kk = 0; kk < 4; ++kk) {
            const int k0 = kk * 32 + g * 8;
            bf16x8 a0 = *reinterpret_cast<const bf16x8*>(&sX[s0 + c][k0]);
            #pragma unroll
            for (int ct = 0; ct < 8; ++ct) {
                bf16x8 bw = *reinterpret_cast<const bf16x8*>(WkT + (ct * 16 + c) * 128 + k0);
                ak[ct] = MFMA16(a0, bw, ak[ct]);
            }
        }
        #pragma unroll
        for (int ct = 0; ct < 8; ++ct) {
            const int h = ct * 16 + c;
            const float bkv = bk[h];
            #pragma unroll
            for (int r = 0; r < 4; ++r)
                sKV[s0 + g * 4 + r][h] = (bf16)(ak[ct][r] + bkv);
        }
    }
    {
        f32x4 av[8];
        #pragma unroll
        for (int ct = 0; ct < 8; ++ct) av[ct] = FZ;
        #pragma unroll
        for (int kk = 0; kk < 4; ++kk) {
            const int k0 = kk * 32 + g * 8;
            bf16x8 a0 = *reinterpret_cast<const bf16x8*>(&sX[s0 + c][k0]);
            #pragma unroll
            for (int ct = 0; ct < 8; ++ct) {
                bf16x8 bw = *reinterpret_cast<const bf16x8*>(WvT + (ct * 16 + c) * 128 + k0);
                av[ct] = MFMA16(a0, bw, av[ct]);
            }
        }
        #pragma unroll
        for (int ct = 0; ct < 8; ++ct) {
            const float bvv = bv[ct * 16 + c];
            #pragma unroll
            for (int r = 0; r < 4; ++r) vpk[ct][r] = (bf16)(av[ct][r] + bvv);
        }
    }
    {
        #pragma unroll
        for (int ct = 0; ct < 8; ++ct) {
            const int h = ct * 16 + c;
            const float bqv = bq[h];
            #pragma unroll
            for (int r = 0; r < 4; ++r)
                sX[s0 + g * 4 + r][h] = (bf16)(aq[ct][r] + bqv);
        }
    }

    __syncthreads();

    const float rs = 0.08838834764831845f;
    float l0 = 1.f;
    {
        f32x4 sc[8];
        #pragma unroll
        for (int rt = 0; rt < 8; ++rt) sc[rt] = FZ;
        #pragma unroll
        for (int kk = 0; kk < 4; ++kk) {
            const int k0 = kk * 32 + g * 8;
            bf16x8 q0 = *reinterpret_cast<const bf16x8*>(&sX[s0 + c][k0]);
            #pragma unroll
            for (int rt = 0; rt < 8; ++rt) {
                bf16x8 akf = *reinterpret_cast<const bf16x8*>(&sKV[rt * 16 + c][k0]);
                sc[rt] = MFMA16(akf, q0, sc[rt]);
            }
        }
        float m = -3.0e38f;
        #pragma unroll
        for (int rt = 0; rt < 8; ++rt)
            #pragma unroll
            for (int r = 0; r < 4; ++r) m = fmaxf(m, sc[rt][r]);
        m = fmaxf(m, __shfl_xor(m, 16));
        m = fmaxf(m, __shfl_xor(m, 32));
        float ls = 0.f, wsum = 0.f;
        #pragma unroll
        for (int rt = 0; rt < 8; ++rt) {
            #pragma unroll
            for (int r = 0; r < 4; ++r) {
                float p = __expf((sc[rt][r] - m) * rs);
                sc[rt][r] = p;
                ls += p;
                wsum += p * sTm[rt * 16 + g * 4 + r];
            }
        }
        ls   += __shfl_xor(ls, 16);   ls   += __shfl_xor(ls, 32);
        wsum += __shfl_xor(wsum, 16); wsum += __shfl_xor(wsum, 32);
        l0 = ls;
        if (g == 0)
            out[(size_t)67108864 + (size_t)bn * 128 + s0 + c] = 1.0f - wsum / ls;
        #pragma unroll
        for (int rt = 0; rt < 8; ++rt) {
            bf16x4 pk;
            #pragma unroll
            for (int r = 0; r < 4; ++r) pk[r] = (bf16)sc[rt][r];
            *reinterpret_cast<bf16x4*>(&sX[s0 + c][rt * 16 + g * 4]) = pk;
        }
    }

    __syncthreads();
    {
        #pragma unroll
        for (int ct = 0; ct < 8; ++ct)
            *reinterpret_cast<bf16x4*>(&sKV[ct * 16 + c][s0 + g * 4]) = vpk[ct];
    }
    __syncthreads();

    {
        f32x4 rc[8];
        #pragma unroll
        for (int rt = 0; rt < 8; ++rt) rc[rt] = FZ;
        #pragma unroll
        for (int kk = 0; kk < 4; ++kk) {
            const int k0 = kk * 32 + g * 8;
            bf16x8 p0 = *reinterpret_cast<const bf16x8*>(&sX[s0 + c][k0]);
            #pragma unroll
            for (int rt = 0; rt < 8; ++rt) {
                bf16x8 avf = *reinterpret_cast<const bf16x8*>(&sKV[rt * 16 + c][k0]);
                rc[rt] = MFMA16(avf, p0, rc[rt]);
            }
        }
        const float inv0 = 1.0f / l0;
        #pragma unroll
        for (int rt = 0; rt < 8; ++rt) {
            bf16x4 pk0;
            #pragma unroll
            for (int r = 0; r < 4; ++r) pk0[r] = (bf16)(rc[rt][r] * inv0);
            *reinterpret_cast<bf16x4*>(&sX[s0 + c][rt * 16 + g * 4]) = pk0;
        }
    }

    {
        f32x4 oc[8];
        #pragma unroll
        for (int rt = 0; rt < 8; ++rt) oc[rt] = FZ;
        #pragma unroll
        for (int kk = 0; kk < 4; ++kk) {
            const int k0 = kk * 32 + g * 8;
            bf16x8 r0 = *reinterpret_cast<const bf16x8*>(&sX[s0 + c][k0]);
            #pragma unroll
            for (int rt = 0; rt < 8; ++rt) {
                bf16x8 aw = *reinterpret_cast<const bf16x8*>(WoT + (rt * 16 + c) * 128 + k0);
                oc[rt] = MFMA16(aw, r0, oc[rt]);
            }
        }
        float* outb = out + (size_t)bn * 16384;
        const int s = s0 + c;
        #pragma unroll
        for (int rt = 0; rt < 8; ++rt) {
            const int ho0 = rt * 16 + g * 4;
            const float4 bo4 = *reinterpret_cast<const float4*>(bo + ho0);
            float4 v;
            v.x = oc[rt][0] + bo4.x;
            v.y = oc[rt][1] + bo4.y;
            v.z = oc[rt][2] + bo4.z;
            v.w = oc[rt][3] + bo4.w;
            *reinterpret_cast<float4*>(outb + s * 128 + ho0) = v;
        }
    }
}

extern "C" void kernel_launch(void* const* d_in, const int* in_sizes, int n_in,
                              void* d_out, int out_size, void* d_ws, size_t ws_size,
                              hipStream_t stream)
{
    (void)in_sizes; (void)n_in; (void)out_size;
    const float* xf     = (const float*)d_in[0];
    const float* ex     = (const float*)d_in[1];
    const int*   nf     = (const int*)d_in[2];
    const unsigned char* mask = (const unsigned char*)d_in[3];
    const float* W_in   = (const float*)d_in[4];
    const float* b_in   = (const float*)d_in[5];
    const float* W_t    = (const float*)d_in[6];
    const float* b_t    = (const float*)d_in[7];
    const float* E_node = (const float*)d_in[8];
    const float* W_q    = (const float*)d_in[9];
    const float* b_q    = (const float*)d_in[10];
    const float* W_k    = (const float*)d_in[11];
    const float* b_k    = (const float*)d_in[12];
    const float* W_v    = (const float*)d_in[13];
    const float* b_v    = (const float*)d_in[14];
    const float* W_o    = (const float*)d_in[15];
    const float* b_o    = (const float*)d_in[16];
    float* out = (float*)d_out;

    // ws layout:
    //   [0,163840)            wsW: 5x bf16 128x128 transposed weights
    //   [163840,1212416)      biasT f32 [16][128][128] (t fastest)
    //   [1212416,1343488)     npart f32 [256][128]
    //   [1343488,+128MB)      gQ bf16 [4096][128][128]
    //   (+128MB)              gK
    //   (+128MB)              gVT (V^T: [bn][h][t])
    //   (+2MB)                gTm f32 [4096][128]
    const size_t OFF_Q  = 1343488;
    const size_t SZ_QKV = (size_t)4096 * 16384 * 2;
    const size_t OFF_K  = OFF_Q + SZ_QKV;
    const size_t OFF_VT = OFF_K + SZ_QKV;
    const size_t OFF_TM = OFF_VT + SZ_QKV;
    const size_t REQ    = OFF_TM + (size_t)4096 * 128 * 4;

    bf16*  wsW    = (bf16*)d_ws;
    float* biasT  = (float*)((char*)d_ws + 163840);
    float* npart  = (float*)((char*)d_ws + 1212416);

    prep_weights<<<320, 256, 0, stream>>>(W_in, W_q, W_k, W_v, W_o, wsW);
    prep_npart<<<256, 128, 0, stream>>>(nf, E_node, W_in, npart);
    prep_bias<<<2048, 128, 0, stream>>>(ex, W_t, b_t, W_in, b_in, biasT);

    if (ws_size >= REQ) {
        bf16*  gQ  = (bf16*)((char*)d_ws + OFF_Q);
        bf16*  gK  = (bf16*)((char*)d_ws + OFF_K);
        bf16*  gVT = (bf16*)((char*)d_ws + OFF_VT);
        float* gTm = (float*)((char*)d_ws + OFF_TM);
        k1_proj<<<8192, 256, 0, stream>>>(xf, mask, wsW, biasT, npart,
                                          b_q, b_k, b_v, gQ, gK, gVT, gTm);
        k2_attn<<<8192, 256, 0, stream>>>(gQ, gK, gVT, gTm, wsW, b_o, out);
    } else {
        fused_r3<<<4096, 512, 0, stream>>>(xf, mask, wsW, biasT, npart,
                                           b_q, b_k, b_v, b_o, out);
    }
}

// Round 5
// 423.501 us; speedup vs baseline: 2.4598x; 2.4598x over previous
//
#include <hip/hip_runtime.h>
#include <hip/hip_bf16.h>
#include <stdint.h>

// TemporalAttention for MI355X (gfx950). B=16, N=256, T=128, H=128.
// R5: fused kernel with LDS-STAGED WEIGHTS (double-buffered 2x32KB, XOR-swizzled)
//     so every MFMA B-fragment is a ds_read_b128, not a global load.
//     4 waves x 32 rows/wave (16 MFMA per 10 LDS reads). GEMM order G1->K->V->Q.
//     Weight stage: global->reg issued BEFORE the covering GEMM, ds_write after (T14).

typedef __bf16 bf16;
typedef __bf16 bf16x4 __attribute__((ext_vector_type(4)));
typedef __bf16 bf16x8 __attribute__((ext_vector_type(8)));
typedef float  f32x4  __attribute__((ext_vector_type(4)));

#define MFMA16(a, b, c) __builtin_amdgcn_mfma_f32_16x16x32_bf16((a), (b), (c), 0, 0, 0)

__device__ __forceinline__ int allBytesNonzero(unsigned v) {
    return ((v - 0x01010101u) & ~v & 0x80808080u) == 0u;
}

__device__ __forceinline__ bf16x8 cvt8(const float* p) {
    float4 f0 = *reinterpret_cast<const float4*>(p);
    float4 f1 = *reinterpret_cast<const float4*>(p + 4);
    bf16x8 r;
    r[0] = (bf16)f0.x; r[1] = (bf16)f0.y; r[2] = (bf16)f0.z; r[3] = (bf16)f0.w;
    r[4] = (bf16)f1.x; r[5] = (bf16)f1.y; r[6] = (bf16)f1.z; r[7] = (bf16)f1.w;
    return r;
}

// branchless erf-GELU, A&S 7.1.26 (|err| < 1.5e-7)
__device__ __forceinline__ float gelu_erf(float v) {
    float x  = v * 0.70710678118654752f;
    float ax = fabsf(x);
    float t  = __builtin_amdgcn_rcpf(1.0f + 0.3275911f * ax);
    float p  = ((((1.061405429f * t - 1.453152027f) * t + 1.421413741f) * t
                 - 0.284496736f) * t + 0.254829592f) * t;
    float er = 1.0f - p * __expf(-ax * ax);
    er = copysignf(er, x);
    return 0.5f * v * (1.0f + er);
}

// Swizzled weight-fragment read from a 32KB LDS weight slot.
// Logical (row, k0..k0+7) lives at elem row*128 + (k0 ^ ((row&15)<<3)).
__device__ __forceinline__ bf16x8 ldw(const bf16* w, int row, int k0) {
    return *reinterpret_cast<const bf16x8*>(w + row * 128 + (k0 ^ ((row & 15) << 3)));
}

// ---- pre-kernel 1: transpose W1(=W_in[0:128]), Wq, Wk, Wv, Wo to bf16 [h][k] ----
__global__ void prep_weights(const float* __restrict__ W_in,
                             const float* __restrict__ Wq, const float* __restrict__ Wk,
                             const float* __restrict__ Wv, const float* __restrict__ Wo,
                             bf16* __restrict__ dst)
{
    int idx = blockIdx.x * 256 + threadIdx.x;
    if (idx >= 5 * 16384) return;
    int m = idx >> 14, r = idx & 16383;
    int h = r >> 7, k = r & 127;
    const float* src = (m == 0) ? W_in : (m == 1) ? Wq : (m == 2) ? Wk : (m == 3) ? Wv : Wo;
    dst[(m << 14) + h * 128 + k] = (bf16)src[k * 128 + h];  // dst[m][h][k] = W[k][h]
}

// ---- pre-kernel 2: npart[n][h] = E_node[nf[n]] @ W_in[256:384] (f32) ----
__global__ void prep_npart(const int* __restrict__ nf, const float* __restrict__ E_node,
                           const float* __restrict__ W_in, float* __restrict__ npart)
{
    int n = blockIdx.x, h = threadIdx.x;
    int node = nf[n];
    const float* e = E_node + node * 128;
    float acc = 0.f;
    for (int k = 0; k < 128; ++k) acc += e[k] * W_in[(256 + k) * 128 + h];
    npart[n * 128 + h] = acc;
}

// ---- pre-kernel 3: biasT[b][h][t] (t fastest for float4 epilogue loads) ----
__global__ void prep_bias(const float* __restrict__ ex, const float* __restrict__ W_t,
                          const float* __restrict__ b_t, const float* __restrict__ W_in,
                          const float* __restrict__ b_in, float* __restrict__ biasT)
{
    const int bt = blockIdx.x;          // b*128 + t
    const int b = bt >> 7;
    const int t = bt & 127;
    const int h = threadIdx.x;
    __shared__ float te[128];
    float v = b_t[h];
    const float* exr = ex + (size_t)bt * 32;
    for (int d = 0; d < 32; ++d) v += exr[d] * W_t[d * 128 + h];
    te[h] = v;
    __syncthreads();
    float acc = b_in[h];
    const float ninv = -9.210340371976184f / 128.0f;   // -ln(10000)/H
    for (int j = 0; j < 64; ++j) {
        float div = expf((float)(2 * j) * ninv);
        float ang = (float)t * div;
        acc += sinf(ang) * W_in[(2 * j) * 128 + h] + cosf(ang) * W_in[(2 * j + 1) * 128 + h];
    }
    for (int k = 0; k < 128; ++k) acc += te[k] * W_in[(128 + k) * 128 + h];
    biasT[(size_t)b * 16384 + h * 128 + t] = acc;
}

// ---- main fused kernel: 1 block per (b,n), 4 waves, wave w owns rows [32w,32w+32) ----
// MFMA 16x16x32 layouts: A row=lane&15,k=(lane>>4)*8+j; B col=lane&15;
// C/D col=lane&15, row=(lane>>4)*4+reg.
#define STAGE_ISSUE(SRC)                                                        \
    {                                                                           \
        _Pragma("unroll")                                                       \
        for (int i = 0; i < 8; ++i)                                             \
            stg[i] = *reinterpret_cast<const bf16x8*>((SRC) + (tid + i * 256) * 8); \
    }
#define STAGE_WRITE(BUF)                                                        \
    {                                                                           \
        _Pragma("unroll")                                                       \
        for (int i = 0; i < 8; ++i) {                                           \
            int m_ = tid + i * 256;                                             \
            int row_ = m_ >> 4, slot_ = m_ & 15;                                \
            *reinterpret_cast<bf16x8*>(&sW[BUF][row_ * 128 + 8 * (slot_ ^ (row_ & 15))]) = stg[i]; \
        }                                                                       \
    }

__global__ __launch_bounds__(256, 1) void fused_main(
    const float* __restrict__ xf, const unsigned char* __restrict__ mask,
    const bf16* __restrict__ wsW, const float* __restrict__ biasT,
    const float* __restrict__ npart,
    const float* __restrict__ bq, const float* __restrict__ bk,
    const float* __restrict__ bv, const float* __restrict__ bo,
    float* __restrict__ out)
{
    const bf16* W1T = wsW;
    const bf16* WqT = wsW + 16384;
    const bf16* WkT = wsW + 32768;
    const bf16* WvT = wsW + 49152;
    const bf16* WoT = wsW + 65536;

    // data tiles: stride 136 elems = 272B (2-way bank alias = free)
    __shared__ bf16 sX[128][136];    // X -> Q -> P -> rec (wave-private row transitions)
    __shared__ bf16 sKV[128][136];   // K[t][h] -> V^T[h][t]
    __shared__ bf16 sW[2][16384];    // double-buffered weight slots (XOR-swizzled)
    __shared__ float sTm[128];

    const int bn = blockIdx.x;
    const int b  = bn >> 8;
    const int n  = bn & 255;
    const int tid  = (int)threadIdx.x;
    const int w    = tid >> 6;      // 0..3
    const int lane = tid & 63;
    const int c = lane & 15;
    const int g = lane >> 4;
    const int s0 = w << 5;          // 32 rows per wave

    const f32x4 FZ = {0.f, 0.f, 0.f, 0.f};
    bf16x8 stg[8];

    // ---- t_mask[t] = all(mask[b,n,t,:]) ----
    if (tid < 128) {
        const uint4* mp = reinterpret_cast<const uint4*>(mask + ((size_t)bn * 128 + tid) * 128);
        int ok = 1;
        #pragma unroll
        for (int i = 0; i < 8; ++i) {
            uint4 u = mp[i];
            ok &= allBytesNonzero(u.x) & allBytesNonzero(u.y)
                & allBytesNonzero(u.z) & allBytesNonzero(u.w);
        }
        sTm[tid] = ok ? 1.0f : 0.0f;
    }

    // ---- stage W1 -> sW[0] ----
    STAGE_ISSUE(W1T);
    STAGE_WRITE(0);
    __syncthreads();                      // #1: publishes sW[0]=W1

    // ---------- GEMM1: X = gelu(xf@W1 + biasT + npart) -> sX ----------
    STAGE_ISSUE(WkT);                     // Wk loads fly during GEMM1
    {
        f32x4 acc[2][8];
        #pragma unroll
        for (int rt = 0; rt < 2; ++rt)
            #pragma unroll
            for (int ct = 0; ct < 8; ++ct) acc[rt][ct] = FZ;
        const float* xfb = xf + (size_t)bn * 16384;
        #pragma unroll
        for (int kk = 0; kk < 4; ++kk) {
            const int k0 = kk * 32 + g * 8;
            bf16x8 a0 = cvt8(xfb + (s0 + c) * 128 + k0);
            bf16x8 a1 = cvt8(xfb + (s0 + 16 + c) * 128 + k0);
            #pragma unroll
            for (int ct = 0; ct < 8; ++ct) {
                bf16x8 bw = ldw(&sW[0][0], ct * 16 + c, k0);
                acc[0][ct] = MFMA16(a0, bw, acc[0][ct]);
                acc[1][ct] = MFMA16(a1, bw, acc[1][ct]);
            }
        }
        const float* biasB = biasT + (size_t)b * 16384;
        const float* npRow = npart + n * 128;
        #pragma unroll
        for (int ct = 0; ct < 8; ++ct) {
            const int h = ct * 16 + c;
            const float npv = npRow[h];
            #pragma unroll
            for (int rt = 0; rt < 2; ++rt) {
                const int t0 = s0 + rt * 16 + g * 4;
                const float4 bb = *reinterpret_cast<const float4*>(biasB + h * 128 + t0);
                const float bbr[4] = {bb.x, bb.y, bb.z, bb.w};
                #pragma unroll
                for (int r = 0; r < 4; ++r)
                    sX[t0 + r][h] = (bf16)gelu_erf(acc[rt][ct][r] + bbr[r] + npv);
            }
        }
    }
    STAGE_WRITE(1);                       // Wk -> sW[1]
    __syncthreads();                      // #2: publishes sW[1]=Wk, sX=X

    // ---------- K = X@Wk + bk -> sKV ----------
    STAGE_ISSUE(WvT);
    {
        f32x4 acc[2][8];
        #pragma unroll
        for (int rt = 0; rt < 2; ++rt)
            #pragma unroll
            for (int ct = 0; ct < 8; ++ct) acc[rt][ct] = FZ;
        #pragma unroll
        for (int kk = 0; kk < 4; ++kk) {
            const int k0 = kk * 32 + g * 8;
            bf16x8 a0 = *reinterpret_cast<const bf16x8*>(&sX[s0 + c][k0]);
            bf16x8 a1 = *reinterpret_cast<const bf16x8*>(&sX[s0 + 16 + c][k0]);
            #pragma unroll
            for (int ct = 0; ct < 8; ++ct) {
                bf16x8 bw = ldw(&sW[1][0], ct * 16 + c, k0);
                acc[0][ct] = MFMA16(a0, bw, acc[0][ct]);
                acc[1][ct] = MFMA16(a1, bw, acc[1][ct]);
            }
        }
        #pragma unroll
        for (int ct = 0; ct < 8; ++ct) {
            const int h = ct * 16 + c;
            const float bkv = bk[h];
            #pragma unroll
            for (int rt = 0; rt < 2; ++rt)
                #pragma unroll
                for (int r = 0; r < 4; ++r)
                    sKV[s0 + rt * 16 + g * 4 + r][h] = (bf16)(acc[rt][ct][r] + bkv);
        }
    }
    STAGE_WRITE(0);                       // Wv -> sW[0] (W1 dead)
    __syncthreads();                      // #3

    // ---------- V = X@Wv + bv -> vpk regs ----------
    bf16x4 vpk[2][8];
    STAGE_ISSUE(WqT);
    {
        f32x4 acc[2][8];
        #pragma unroll
        for (int rt = 0; rt < 2; ++rt)
            #pragma unroll
            for (int ct = 0; ct < 8; ++ct) acc[rt][ct] = FZ;
        #pragma unroll
        for (int kk = 0; kk < 4; ++kk) {
            const int k0 = kk * 32 + g * 8;
            bf16x8 a0 = *reinterpret_cast<const bf16x8*>(&sX[s0 + c][k0]);
            bf16x8 a1 = *reinterpret_cast<const bf16x8*>(&sX[s0 + 16 + c][k0]);
            #pragma unroll
            for (int ct = 0; ct < 8; ++ct) {
                bf16x8 bw = ldw(&sW[0][0], ct * 16 + c, k0);
                acc[0][ct] = MFMA16(a0, bw, acc[0][ct]);
                acc[1][ct] = MFMA16(a1, bw, acc[1][ct]);
            }
        }
        #pragma unroll
        for (int ct = 0; ct < 8; ++ct) {
            const float bvv = bv[ct * 16 + c];
            #pragma unroll
            for (int rt = 0; rt < 2; ++rt)
                #pragma unroll
                for (int r = 0; r < 4; ++r)
                    vpk[rt][ct][r] = (bf16)(acc[rt][ct][r] + bvv);
        }
    }
    STAGE_WRITE(1);                       // Wq -> sW[1] (Wk dead)
    __syncthreads();                      // #4

    // ---------- Q = X@Wq + bq -> overwrite sX own rows ----------
    STAGE_ISSUE(WoT);
    {
        f32x4 acc[2][8];
        #pragma unroll
        for (int rt = 0; rt < 2; ++rt)
            #pragma unroll
            for (int ct = 0; ct < 8; ++ct) acc[rt][ct] = FZ;
        #pragma unroll
        for (int kk = 0; kk < 4; ++kk) {
            const int k0 = kk * 32 + g * 8;
            bf16x8 a0 = *reinterpret_cast<const bf16x8*>(&sX[s0 + c][k0]);
            bf16x8 a1 = *reinterpret_cast<const bf16x8*>(&sX[s0 + 16 + c][k0]);
            #pragma unroll
            for (int ct = 0; ct < 8; ++ct) {
                bf16x8 bw = ldw(&sW[1][0], ct * 16 + c, k0);
                acc[0][ct] = MFMA16(a0, bw, acc[0][ct]);
                acc[1][ct] = MFMA16(a1, bw, acc[1][ct]);
            }
        }
        #pragma unroll
        for (int ct = 0; ct < 8; ++ct) {
            const int h = ct * 16 + c;
            const float bqv = bq[h];
            #pragma unroll
            for (int rt = 0; rt < 2; ++rt)
                #pragma unroll
                for (int r = 0; r < 4; ++r)
                    sX[s0 + rt * 16 + g * 4 + r][h] = (bf16)(acc[rt][ct][r] + bqv);
        }
    }
    STAGE_WRITE(0);                       // Wo -> sW[0] (Wv dead)
    __syncthreads();                      // #5: publishes sKV=K, sW[0]=Wo, sTm

    const float rs = 0.08838834764831845f;  // 1/sqrt(128)
    float l0 = 1.f, l1 = 1.f;

    // ---------- scores^T[t][s] = K·Q^T ; softmax over t ; P -> sX own rows ----------
    {
        f32x4 sc[8][2];
        #pragma unroll
        for (int rt = 0; rt < 8; ++rt) { sc[rt][0] = FZ; sc[rt][1] = FZ; }
        #pragma unroll
        for (int kk = 0; kk < 4; ++kk) {
            const int k0 = kk * 32 + g * 8;
            bf16x8 q0 = *reinterpret_cast<const bf16x8*>(&sX[s0 + c][k0]);
            bf16x8 q1 = *reinterpret_cast<const bf16x8*>(&sX[s0 + 16 + c][k0]);
            #pragma unroll
            for (int rt = 0; rt < 8; ++rt) {
                bf16x8 akf = *reinterpret_cast<const bf16x8*>(&sKV[rt * 16 + c][k0]);
                sc[rt][0] = MFMA16(akf, q0, sc[rt][0]);
                sc[rt][1] = MFMA16(akf, q1, sc[rt][1]);
            }
        }
        #pragma unroll
        for (int ct = 0; ct < 2; ++ct) {
            float m = -3.0e38f;
            #pragma unroll
            for (int rt = 0; rt < 8; ++rt)
                #pragma unroll
                for (int r = 0; r < 4; ++r) m = fmaxf(m, sc[rt][ct][r]);
            m = fmaxf(m, __shfl_xor(m, 16));
            m = fmaxf(m, __shfl_xor(m, 32));
            float ls = 0.f, wsum = 0.f;
            #pragma unroll
            for (int rt = 0; rt < 8; ++rt) {
                #pragma unroll
                for (int r = 0; r < 4; ++r) {
                    float p = __expf((sc[rt][ct][r] - m) * rs);
                    sc[rt][ct][r] = p;
                    ls += p;
                    wsum += p * sTm[rt * 16 + g * 4 + r];
                }
            }
            ls   += __shfl_xor(ls, 16);   ls   += __shfl_xor(ls, 32);
            wsum += __shfl_xor(wsum, 16); wsum += __shfl_xor(wsum, 32);
            if (ct == 0) l0 = ls; else l1 = ls;
            if (g == 0)
                out[(size_t)67108864 + (size_t)bn * 128 + s0 + ct * 16 + c] = 1.0f - wsum / ls;
            #pragma unroll
            for (int rt = 0; rt < 8; ++rt) {
                bf16x4 pk;
                #pragma unroll
                for (int r = 0; r < 4; ++r) pk[r] = (bf16)sc[rt][ct][r];
                *reinterpret_cast<bf16x4*>(&sX[s0 + ct * 16 + c][rt * 16 + g * 4]) = pk;
            }
        }
    }

    __syncthreads();                      // #6: all waves done reading sKV(K)

    // ---------- V (regs) -> sKV as V^T[h][t] ----------
    {
        #pragma unroll
        for (int ct = 0; ct < 8; ++ct)
            #pragma unroll
            for (int rt = 0; rt < 2; ++rt)
                *reinterpret_cast<bf16x4*>(&sKV[ct * 16 + c][s0 + rt * 16 + g * 4]) = vpk[rt][ct];
    }

    __syncthreads();                      // #7: publishes sKV=V^T

    // ---------- rec^T[h][s] = V^T·P ; normalize ; rec -> sX own rows ----------
    {
        f32x4 rc[8][2];
        #pragma unroll
        for (int rt = 0; rt < 8; ++rt) { rc[rt][0] = FZ; rc[rt][1] = FZ; }
        #pragma unroll
        for (int kk = 0; kk < 4; ++kk) {
            const int k0 = kk * 32 + g * 8;
            bf16x8 p0 = *reinterpret_cast<const bf16x8*>(&sX[s0 + c][k0]);
            bf16x8 p1 = *reinterpret_cast<const bf16x8*>(&sX[s0 + 16 + c][k0]);
            #pragma unroll
            for (int rt = 0; rt < 8; ++rt) {
                bf16x8 avf = *reinterpret_cast<const bf16x8*>(&sKV[rt * 16 + c][k0]);
                rc[rt][0] = MFMA16(avf, p0, rc[rt][0]);
                rc[rt][1] = MFMA16(avf, p1, rc[rt][1]);
            }
        }
        const float inv0 = __builtin_amdgcn_rcpf(l0);
        const float inv1 = __builtin_amdgcn_rcpf(l1);
        #pragma unroll
        for (int rt = 0; rt < 8; ++rt) {
            bf16x4 pk0, pk1;
            #pragma unroll
            for (int r = 0; r < 4; ++r) {
                pk0[r] = (bf16)(rc[rt][0][r] * inv0);
                pk1[r] = (bf16)(rc[rt][1][r] * inv1);
            }
            *reinterpret_cast<bf16x4*>(&sX[s0 + c][rt * 16 + g * 4]) = pk0;
            *reinterpret_cast<bf16x4*>(&sX[s0 + 16 + c][rt * 16 + g * 4]) = pk1;
        }
    }

    // ---------- out^T[ho][s] = Wo^T·rec^T + bo ; store f32 ----------
    {
        f32x4 oc[8][2];
        #pragma unroll
        for (int rt = 0; rt < 8; ++rt) { oc[rt][0] = FZ; oc[rt][1] = FZ; }
        #pragma unroll
        for (int kk = 0; kk < 4; ++kk) {
            const int k0 = kk * 32 + g * 8;
            bf16x8 r0 = *reinterpret_cast<const bf16x8*>(&sX[s0 + c][k0]);
            bf16x8 r1 = *reinterpret_cast<const bf16x8*>(&sX[s0 + 16 + c][k0]);
            #pragma unroll
            for (int rt = 0; rt < 8; ++rt) {
                bf16x8 aw = ldw(&sW[0][0], rt * 16 + c, k0);
                oc[rt][0] = MFMA16(aw, r0, oc[rt][0]);
                oc[rt][1] = MFMA16(aw, r1, oc[rt][1]);
            }
        }
        float* outb = out + (size_t)bn * 16384;
        #pragma unroll
        for (int ct = 0; ct < 2; ++ct) {
            const int s = s0 + ct * 16 + c;
            #pragma unroll
            for (int rt = 0; rt < 8; ++rt) {
                const int ho0 = rt * 16 + g * 4;
                const float4 bo4 = *reinterpret_cast<const float4*>(bo + ho0);
                float4 v;
                v.x = oc[rt][ct][0] + bo4.x;
                v.y = oc[rt][ct][1] + bo4.y;
                v.z = oc[rt][ct][2] + bo4.z;
                v.w = oc[rt][ct][3] + bo4.w;
                *reinterpret_cast<float4*>(outb + s * 128 + ho0) = v;
            }
        }
    }
}

extern "C" void kernel_launch(void* const* d_in, const int* in_sizes, int n_in,
                              void* d_out, int out_size, void* d_ws, size_t ws_size,
                              hipStream_t stream)
{
    (void)in_sizes; (void)n_in; (void)out_size; (void)ws_size;
    const float* xf     = (const float*)d_in[0];
    const float* ex     = (const float*)d_in[1];
    const int*   nf     = (const int*)d_in[2];
    const unsigned char* mask = (const unsigned char*)d_in[3];
    const float* W_in   = (const float*)d_in[4];
    const float* b_in   = (const float*)d_in[5];
    const float* W_t    = (const float*)d_in[6];
    const float* b_t    = (const float*)d_in[7];
    const float* E_node = (const float*)d_in[8];
    const float* W_q    = (const float*)d_in[9];
    const float* b_q    = (const float*)d_in[10];
    const float* W_k    = (const float*)d_in[11];
    const float* b_k    = (const float*)d_in[12];
    const float* W_v    = (const float*)d_in[13];
    const float* b_v    = (const float*)d_in[14];
    const float* W_o    = (const float*)d_in[15];
    const float* b_o    = (const float*)d_in[16];
    float* out = (float*)d_out;

    // ws layout: [0,163840) 5x bf16 128x128 transposed weights;
    //            [163840,1212416) biasT f32 [16][128][128] (t fastest);
    //            [1212416,1343488) npart f32 [256][128].
    bf16*  wsW    = (bf16*)d_ws;
    float* biasT  = (float*)((char*)d_ws + 163840);
    float* npart  = (float*)((char*)d_ws + 1212416);

    prep_weights<<<320, 256, 0, stream>>>(W_in, W_q, W_k, W_v, W_o, wsW);
    prep_npart<<<256, 128, 0, stream>>>(nf, E_node, W_in, npart);
    prep_bias<<<2048, 128, 0, stream>>>(ex, W_t, b_t, W_in, b_in, biasT);
    fused_main<<<4096, 256, 0, stream>>>(xf, mask, wsW, biasT, npart,
                                         b_q, b_k, b_v, b_o, out);
}

// Round 6
// 352.623 us; speedup vs baseline: 2.9542x; 1.2010x over previous
//
#include <hip/hip_runtime.h>
#include <hip/hip_bf16.h>
#include <stdint.h>

// TemporalAttention for MI355X (gfx950). B=16, N=256, T=128, H=128.
// R6: R5's LDS-staged-weight structure, but 512 threads / 8 waves x 16 rows/wave
//     and __launch_bounds__(512,2) -> 2 waves/SIMD (R5 was 1). Same 2x32KB
//     double-buffered XOR-swizzled weight slots, same 7-barrier schedule.
//     xf A-fragments prefetched to regs before the first barrier.

typedef __bf16 bf16;
typedef __bf16 bf16x4 __attribute__((ext_vector_type(4)));
typedef __bf16 bf16x8 __attribute__((ext_vector_type(8)));
typedef float  f32x4  __attribute__((ext_vector_type(4)));

#define MFMA16(a, b, c) __builtin_amdgcn_mfma_f32_16x16x32_bf16((a), (b), (c), 0, 0, 0)

__device__ __forceinline__ int allBytesNonzero(unsigned v) {
    return ((v - 0x01010101u) & ~v & 0x80808080u) == 0u;
}

__device__ __forceinline__ bf16x8 cvt8(const float* p) {
    float4 f0 = *reinterpret_cast<const float4*>(p);
    float4 f1 = *reinterpret_cast<const float4*>(p + 4);
    bf16x8 r;
    r[0] = (bf16)f0.x; r[1] = (bf16)f0.y; r[2] = (bf16)f0.z; r[3] = (bf16)f0.w;
    r[4] = (bf16)f1.x; r[5] = (bf16)f1.y; r[6] = (bf16)f1.z; r[7] = (bf16)f1.w;
    return r;
}

// branchless erf-GELU, A&S 7.1.26 (|err| < 1.5e-7)
__device__ __forceinline__ float gelu_erf(float v) {
    float x  = v * 0.70710678118654752f;
    float ax = fabsf(x);
    float t  = __builtin_amdgcn_rcpf(1.0f + 0.3275911f * ax);
    float p  = ((((1.061405429f * t - 1.453152027f) * t + 1.421413741f) * t
                 - 0.284496736f) * t + 0.254829592f) * t;
    float er = 1.0f - p * __expf(-ax * ax);
    er = copysignf(er, x);
    return 0.5f * v * (1.0f + er);
}

// Swizzled weight-fragment read from a 32KB LDS weight slot.
// Logical (row, k0..k0+7) lives at elem row*128 + (k0 ^ ((row&15)<<3)).
__device__ __forceinline__ bf16x8 ldw(const bf16* w, int row, int k0) {
    return *reinterpret_cast<const bf16x8*>(w + row * 128 + (k0 ^ ((row & 15) << 3)));
}

// ---- pre-kernel 1: transpose W1(=W_in[0:128]), Wq, Wk, Wv, Wo to bf16 [h][k] ----
__global__ void prep_weights(const float* __restrict__ W_in,
                             const float* __restrict__ Wq, const float* __restrict__ Wk,
                             const float* __restrict__ Wv, const float* __restrict__ Wo,
                             bf16* __restrict__ dst)
{
    int idx = blockIdx.x * 256 + threadIdx.x;
    if (idx >= 5 * 16384) return;
    int m = idx >> 14, r = idx & 16383;
    int h = r >> 7, k = r & 127;
    const float* src = (m == 0) ? W_in : (m == 1) ? Wq : (m == 2) ? Wk : (m == 3) ? Wv : Wo;
    dst[(m << 14) + h * 128 + k] = (bf16)src[k * 128 + h];  // dst[m][h][k] = W[k][h]
}

// ---- pre-kernel 2: npart[n][h] = E_node[nf[n]] @ W_in[256:384] (f32) ----
__global__ void prep_npart(const int* __restrict__ nf, const float* __restrict__ E_node,
                           const float* __restrict__ W_in, float* __restrict__ npart)
{
    int n = blockIdx.x, h = threadIdx.x;
    int node = nf[n];
    const float* e = E_node + node * 128;
    float acc = 0.f;
    for (int k = 0; k < 128; ++k) acc += e[k] * W_in[(256 + k) * 128 + h];
    npart[n * 128 + h] = acc;
}

// ---- pre-kernel 3: biasT[b][h][t] (t fastest for float4 epilogue loads) ----
__global__ void prep_bias(const float* __restrict__ ex, const float* __restrict__ W_t,
                          const float* __restrict__ b_t, const float* __restrict__ W_in,
                          const float* __restrict__ b_in, float* __restrict__ biasT)
{
    const int bt = blockIdx.x;          // b*128 + t
    const int b = bt >> 7;
    const int t = bt & 127;
    const int h = threadIdx.x;
    __shared__ float te[128];
    float v = b_t[h];
    const float* exr = ex + (size_t)bt * 32;
    for (int d = 0; d < 32; ++d) v += exr[d] * W_t[d * 128 + h];
    te[h] = v;
    __syncthreads();
    float acc = b_in[h];
    const float ninv = -9.210340371976184f / 128.0f;   // -ln(10000)/H
    for (int j = 0; j < 64; ++j) {
        float div = expf((float)(2 * j) * ninv);
        float ang = (float)t * div;
        acc += sinf(ang) * W_in[(2 * j) * 128 + h] + cosf(ang) * W_in[(2 * j + 1) * 128 + h];
    }
    for (int k = 0; k < 128; ++k) acc += te[k] * W_in[(128 + k) * 128 + h];
    biasT[(size_t)b * 16384 + h * 128 + t] = acc;
}

// ---- main fused kernel: 1 block per (b,n), 8 waves, wave w owns rows [16w,16w+16) ----
// MFMA 16x16x32 layouts: A row=lane&15,k=(lane>>4)*8+j; B col=lane&15;
// C/D col=lane&15, row=(lane>>4)*4+reg.
#define STAGE_ISSUE(SRC)                                                        \
    {                                                                           \
        _Pragma("unroll")                                                       \
        for (int i = 0; i < 4; ++i)                                             \
            stg[i] = *reinterpret_cast<const bf16x8*>((SRC) + (tid + i * 512) * 8); \
    }
#define STAGE_WRITE(BUF)                                                        \
    {                                                                           \
        _Pragma("unroll")                                                       \
        for (int i = 0; i < 4; ++i) {                                           \
            int m_ = tid + i * 512;                                             \
            int row_ = m_ >> 4, slot_ = m_ & 15;                                \
            *reinterpret_cast<bf16x8*>(&sW[BUF][row_ * 128 + 8 * (slot_ ^ (row_ & 15))]) = stg[i]; \
        }                                                                       \
    }

__global__ __launch_bounds__(512, 2) void fused_main(
    const float* __restrict__ xf, const unsigned char* __restrict__ mask,
    const bf16* __restrict__ wsW, const float* __restrict__ biasT,
    const float* __restrict__ npart,
    const float* __restrict__ bq, const float* __restrict__ bk,
    const float* __restrict__ bv, const float* __restrict__ bo,
    float* __restrict__ out)
{
    const bf16* W1T = wsW;
    const bf16* WqT = wsW + 16384;
    const bf16* WkT = wsW + 32768;
    const bf16* WvT = wsW + 49152;
    const bf16* WoT = wsW + 65536;

    // data tiles: stride 136 elems = 272B (2-way bank alias = free)
    __shared__ bf16 sX[128][136];    // X -> Q -> P -> rec (wave-private row transitions)
    __shared__ bf16 sKV[128][136];   // K[t][h] -> V^T[h][t]
    __shared__ bf16 sW[2][16384];    // double-buffered weight slots (XOR-swizzled)
    __shared__ float sTm[128];

    const int bn = blockIdx.x;
    const int b  = bn >> 8;
    const int n  = bn & 255;
    const int tid  = (int)threadIdx.x;
    const int w    = tid >> 6;      // 0..7
    const int lane = tid & 63;
    const int c = lane & 15;
    const int g = lane >> 4;
    const int s0 = w << 4;          // 16 rows per wave

    const f32x4 FZ = {0.f, 0.f, 0.f, 0.f};
    bf16x8 stg[4];

    // ---- t_mask[t] = all(mask[b,n,t,:]) ----
    if (tid < 128) {
        const uint4* mp = reinterpret_cast<const uint4*>(mask + ((size_t)bn * 128 + tid) * 128);
        int ok = 1;
        #pragma unroll
        for (int i = 0; i < 8; ++i) {
            uint4 u = mp[i];
            ok &= allBytesNonzero(u.x) & allBytesNonzero(u.y)
                & allBytesNonzero(u.z) & allBytesNonzero(u.w);
        }
        sTm[tid] = ok ? 1.0f : 0.0f;
    }

    // ---- stage W1 -> sW[0]; prefetch this wave's xf A-fragments meanwhile ----
    STAGE_ISSUE(W1T);
    bf16x8 af[4];
    {
        const float* xfb = xf + (size_t)bn * 16384;
        #pragma unroll
        for (int kk = 0; kk < 4; ++kk)
            af[kk] = cvt8(xfb + (s0 + c) * 128 + kk * 32 + g * 8);
    }
    STAGE_WRITE(0);
    __syncthreads();                      // #1: publishes sW[0]=W1

    // ---------- GEMM1: X = gelu(xf@W1 + biasT + npart) -> sX rows [s0,s0+16) ----------
    STAGE_ISSUE(WkT);                     // Wk loads fly during GEMM1
    {
        f32x4 acc[8];
        #pragma unroll
        for (int ct = 0; ct < 8; ++ct) acc[ct] = FZ;
        #pragma unroll
        for (int kk = 0; kk < 4; ++kk) {
            const int k0 = kk * 32 + g * 8;
            #pragma unroll
            for (int ct = 0; ct < 8; ++ct) {
                bf16x8 bw = ldw(&sW[0][0], ct * 16 + c, k0);
                acc[ct] = MFMA16(af[kk], bw, acc[ct]);
            }
        }
        const float* biasB = biasT + (size_t)b * 16384;
        const float* npRow = npart + n * 128;
        #pragma unroll
        for (int ct = 0; ct < 8; ++ct) {
            const int h = ct * 16 + c;
            const float npv = npRow[h];
            const int t0 = s0 + g * 4;
            const float4 bb = *reinterpret_cast<const float4*>(biasB + h * 128 + t0);
            const float bbr[4] = {bb.x, bb.y, bb.z, bb.w};
            #pragma unroll
            for (int r = 0; r < 4; ++r)
                sX[t0 + r][h] = (bf16)gelu_erf(acc[ct][r] + bbr[r] + npv);
        }
    }
    STAGE_WRITE(1);                       // Wk -> sW[1]
    __syncthreads();                      // #2: publishes sW[1]=Wk, sX=X

    // ---------- K = X@Wk + bk -> sKV ----------
    STAGE_ISSUE(WvT);
    {
        f32x4 acc[8];
        #pragma unroll
        for (int ct = 0; ct < 8; ++ct) acc[ct] = FZ;
        #pragma unroll
        for (int kk = 0; kk < 4; ++kk) {
            const int k0 = kk * 32 + g * 8;
            bf16x8 a0 = *reinterpret_cast<const bf16x8*>(&sX[s0 + c][k0]);
            #pragma unroll
            for (int ct = 0; ct < 8; ++ct) {
                bf16x8 bw = ldw(&sW[1][0], ct * 16 + c, k0);
                acc[ct] = MFMA16(a0, bw, acc[ct]);
            }
        }
        #pragma unroll
        for (int ct = 0; ct < 8; ++ct) {
            const int h = ct * 16 + c;
            const float bkv = bk[h];
            #pragma unroll
            for (int r = 0; r < 4; ++r)
                sKV[s0 + g * 4 + r][h] = (bf16)(acc[ct][r] + bkv);
        }
    }
    STAGE_WRITE(0);                       // Wv -> sW[0] (W1 dead)
    __syncthreads();                      // #3

    // ---------- V = X@Wv + bv -> vpk regs ----------
    bf16x4 vpk[8];
    STAGE_ISSUE(WqT);
    {
        f32x4 acc[8];
        #pragma unroll
        for (int ct = 0; ct < 8; ++ct) acc[ct] = FZ;
        #pragma unroll
        for (int kk = 0; kk < 4; ++kk) {
            const int k0 = kk * 32 + g * 8;
            bf16x8 a0 = *reinterpret_cast<const bf16x8*>(&sX[s0 + c][k0]);
            #pragma unroll
            for (int ct = 0; ct < 8; ++ct) {
                bf16x8 bw = ldw(&sW[0][0], ct * 16 + c, k0);
                acc[ct] = MFMA16(a0, bw, acc[ct]);
            }
        }
        #pragma unroll
        for (int ct = 0; ct < 8; ++ct) {
            const float bvv = bv[ct * 16 + c];
            #pragma unroll
            for (int r = 0; r < 4; ++r)
                vpk[ct][r] = (bf16)(acc[ct][r] + bvv);
        }
    }
    STAGE_WRITE(1);                       // Wq -> sW[1] (Wk dead)
    __syncthreads();                      // #4

    // ---------- Q = X@Wq + bq -> overwrite sX own rows ----------
    STAGE_ISSUE(WoT);
    {
        f32x4 acc[8];
        #pragma unroll
        for (int ct = 0; ct < 8; ++ct) acc[ct] = FZ;
        #pragma unroll
        for (int kk = 0; kk < 4; ++kk) {
            const int k0 = kk * 32 + g * 8;
            bf16x8 a0 = *reinterpret_cast<const bf16x8*>(&sX[s0 + c][k0]);
            #pragma unroll
            for (int ct = 0; ct < 8; ++ct) {
                bf16x8 bw = ldw(&sW[1][0], ct * 16 + c, k0);
                acc[ct] = MFMA16(a0, bw, acc[ct]);
            }
        }
        #pragma unroll
        for (int ct = 0; ct < 8; ++ct) {
            const int h = ct * 16 + c;
            const float bqv = bq[h];
            #pragma unroll
            for (int r = 0; r < 4; ++r)
                sX[s0 + g * 4 + r][h] = (bf16)(acc[ct][r] + bqv);
        }
    }
    STAGE_WRITE(0);                       // Wo -> sW[0] (Wv dead)
    __syncthreads();                      // #5: publishes sKV=K, sW[0]=Wo, sTm

    const float rs = 0.08838834764831845f;  // 1/sqrt(128)
    float l0 = 1.f;

    // ---------- scores^T[t][s] = K·Q^T ; softmax over t ; P -> sX own rows ----------
    {
        f32x4 sc[8];
        #pragma unroll
        for (int rt = 0; rt < 8; ++rt) sc[rt] = FZ;
        #pragma unroll
        for (int kk = 0; kk < 4; ++kk) {
            const int k0 = kk * 32 + g * 8;
            bf16x8 q0 = *reinterpret_cast<const bf16x8*>(&sX[s0 + c][k0]);
            #pragma unroll
            for (int rt = 0; rt < 8; ++rt) {
                bf16x8 akf = *reinterpret_cast<const bf16x8*>(&sKV[rt * 16 + c][k0]);
                sc[rt] = MFMA16(akf, q0, sc[rt]);
            }
        }
        float m = -3.0e38f;
        #pragma unroll
        for (int rt = 0; rt < 8; ++rt)
            #pragma unroll
            for (int r = 0; r < 4; ++r) m = fmaxf(m, sc[rt][r]);
        m = fmaxf(m, __shfl_xor(m, 16));
        m = fmaxf(m, __shfl_xor(m, 32));
        float ls = 0.f, wsum = 0.f;
        #pragma unroll
        for (int rt = 0; rt < 8; ++rt) {
            #pragma unroll
            for (int r = 0; r < 4; ++r) {
                float p = __expf((sc[rt][r] - m) * rs);
                sc[rt][r] = p;
                ls += p;
                wsum += p * sTm[rt * 16 + g * 4 + r];
            }
        }
        ls   += __shfl_xor(ls, 16);   ls   += __shfl_xor(ls, 32);
        wsum += __shfl_xor(wsum, 16); wsum += __shfl_xor(wsum, 32);
        l0 = ls;
        if (g == 0)
            out[(size_t)67108864 + (size_t)bn * 128 + s0 + c] = 1.0f - wsum / ls;
        #pragma unroll
        for (int rt = 0; rt < 8; ++rt) {
            bf16x4 pk;
            #pragma unroll
            for (int r = 0; r < 4; ++r) pk[r] = (bf16)sc[rt][r];
            *reinterpret_cast<bf16x4*>(&sX[s0 + c][rt * 16 + g * 4]) = pk;
        }
    }

    __syncthreads();                      // #6: all waves done reading sKV(K)

    // ---------- V (regs) -> sKV as V^T[h][t] ----------
    {
        #pragma unroll
        for (int ct = 0; ct < 8; ++ct)
            *reinterpret_cast<bf16x4*>(&sKV[ct * 16 + c][s0 + g * 4]) = vpk[ct];
    }

    __syncthreads();                      // #7: publishes sKV=V^T

    // ---------- rec^T[h][s] = V^T·P ; normalize ; rec -> sX own rows ----------
    {
        f32x4 rc[8];
        #pragma unroll
        for (int rt = 0; rt < 8; ++rt) rc[rt] = FZ;
        #pragma unroll
        for (int kk = 0; kk < 4; ++kk) {
            const int k0 = kk * 32 + g * 8;
            bf16x8 p0 = *reinterpret_cast<const bf16x8*>(&sX[s0 + c][k0]);
            #pragma unroll
            for (int rt = 0; rt < 8; ++rt) {
                bf16x8 avf = *reinterpret_cast<const bf16x8*>(&sKV[rt * 16 + c][k0]);
                rc[rt] = MFMA16(avf, p0, rc[rt]);
            }
        }
        const float inv0 = __builtin_amdgcn_rcpf(l0);
        #pragma unroll
        for (int rt = 0; rt < 8; ++rt) {
            bf16x4 pk0;
            #pragma unroll
            for (int r = 0; r < 4; ++r) pk0[r] = (bf16)(rc[rt][r] * inv0);
            *reinterpret_cast<bf16x4*>(&sX[s0 + c][rt * 16 + g * 4]) = pk0;
        }
    }

    // ---------- out^T[ho][s] = Wo^T·rec^T + bo ; store f32 ----------
    {
        f32x4 oc[8];
        #pragma unroll
        for (int rt = 0; rt < 8; ++rt) oc[rt] = FZ;
        #pragma unroll
        for (int kk = 0; kk < 4; ++kk) {
            const int k0 = kk * 32 + g * 8;
            bf16x8 r0 = *reinterpret_cast<const bf16x8*>(&sX[s0 + c][k0]);
            #pragma unroll
            for (int rt = 0; rt < 8; ++rt) {
                bf16x8 aw = ldw(&sW[0][0], rt * 16 + c, k0);
                oc[rt] = MFMA16(aw, r0, oc[rt]);
            }
        }
        float* outb = out + (size_t)bn * 16384;
        const int s = s0 + c;
        #pragma unroll
        for (int rt = 0; rt < 8; ++rt) {
            const int ho0 = rt * 16 + g * 4;
            const float4 bo4 = *reinterpret_cast<const float4*>(bo + ho0);
            float4 v;
            v.x = oc[rt][0] + bo4.x;
            v.y = oc[rt][1] + bo4.y;
            v.z = oc[rt][2] + bo4.z;
            v.w = oc[rt][3] + bo4.w;
            *reinterpret_cast<float4*>(outb + s * 128 + ho0) = v;
        }
    }
}

extern "C" void kernel_launch(void* const* d_in, const int* in_sizes, int n_in,
                              void* d_out, int out_size, void* d_ws, size_t ws_size,
                              hipStream_t stream)
{
    (void)in_sizes; (void)n_in; (void)out_size; (void)ws_size;
    const float* xf     = (const float*)d_in[0];
    const float* ex     = (const float*)d_in[1];
    const int*   nf     = (const int*)d_in[2];
    const unsigned char* mask = (const unsigned char*)d_in[3];
    const float* W_in   = (const float*)d_in[4];
    const float* b_in   = (const float*)d_in[5];
    const float* W_t    = (const float*)d_in[6];
    const float* b_t    = (const float*)d_in[7];
    const float* E_node = (const float*)d_in[8];
    const float* W_q    = (const float*)d_in[9];
    const float* b_q    = (const float*)d_in[10];
    const float* W_k    = (const float*)d_in[11];
    const float* b_k    = (const float*)d_in[12];
    const float* W_v    = (const float*)d_in[13];
    const float* b_v    = (const float*)d_in[14];
    const float* W_o    = (const float*)d_in[15];
    const float* b_o    = (const float*)d_in[16];
    float* out = (float*)d_out;

    // ws layout: [0,163840) 5x bf16 128x128 transposed weights;
    //            [163840,1212416) biasT f32 [16][128][128] (t fastest);
    //            [1212416,1343488) npart f32 [256][128].
    bf16*  wsW    = (bf16*)d_ws;
    float* biasT  = (float*)((char*)d_ws + 163840);
    float* npart  = (float*)((char*)d_ws + 1212416);

    prep_weights<<<320, 256, 0, stream>>>(W_in, W_q, W_k, W_v, W_o, wsW);
    prep_npart<<<256, 128, 0, stream>>>(nf, E_node, W_in, npart);
    prep_bias<<<2048, 128, 0, stream>>>(ex, W_t, b_t, W_in, b_in, biasT);
    fused_main<<<4096, 512, 0, stream>>>(xf, mask, wsW, biasT, npart,
                                         b_q, b_k, b_v, b_o, out);
}